// Round 8
// baseline (290.762 us; speedup 1.0000x reference)
//
#include <hip/hip_runtime.h>

typedef __attribute__((ext_vector_type(8))) short bfrag;   // 8 bf16 (4 VGPRs) MFMA operand
typedef __attribute__((ext_vector_type(4))) short s4;      // 4 bf16 (2 VGPRs)
typedef __attribute__((ext_vector_type(4))) float f4;      // MFMA accumulator
typedef unsigned short u16;
typedef __attribute__((ext_vector_type(4))) unsigned short u16x4;

#define L2T 0.20762050593046f   // log2(10000)/64

__device__ inline u16 f2bf(float x) {
    unsigned u = __builtin_bit_cast(unsigned, x);
    u += 0x7FFFu + ((u >> 16) & 1u);   // round-to-nearest-even
    return (u16)(u >> 16);
}

__device__ inline void gload16(const u16* g, u16* l) {
    // async global->LDS, 16B/lane; LDS dst = wave-uniform base + lane*16
    __builtin_amdgcn_global_load_lds((const __attribute__((address_space(1))) u16*)g,
                                     (__attribute__((address_space(3))) u16*)l, 16, 0, 0);
}

// ---------------- fused prep: cast X/wq/wk/wv/wo -> bf16, concat biases ----------------
__global__ __launch_bounds__(256) void prep(const float* __restrict__ X,  const float* __restrict__ wq,
                                            const float* __restrict__ wk, const float* __restrict__ wv,
                                            const float* __restrict__ wo, const float* __restrict__ bq,
                                            const float* __restrict__ bk, const float* __restrict__ bv,
                                            u16* __restrict__ Xb, u16* __restrict__ Wqkv,
                                            u16* __restrict__ Wo_, float* __restrict__ biasqkv) {
    const int v = blockIdx.x * 256 + threadIdx.x;
    const float* src; u16* dst; int idx;
    if (v < 1048576)      { src = X;  dst = Xb;              idx = v; }
    else if (v < 2097152) { src = wq; dst = Wqkv;            idx = v - 1048576; }
    else if (v < 2359296) { src = wk; dst = Wqkv + 4194304;  idx = v - 2097152; }
    else if (v < 2621440) { src = wv; dst = Wqkv + 5242880;  idx = v - 2359296; }
    else if (v < 3670016) { src = wo; dst = Wo_;             idx = v - 2621440; }
    else {
        const int b = v - 3670016;   // 768 float4 = 3072 bias floats
        const float* s = (b < 512) ? (bq + b * 4) : (b < 640) ? (bk + (b - 512) * 4) : (bv + (b - 640) * 4);
        *(float4*)(biasqkv + b * 4) = *(const float4*)s;
        return;
    }
    float4 t = *(const float4*)(src + (size_t)idx * 4);
    u16x4 o;
    o.x = f2bf(t.x); o.y = f2bf(t.y); o.z = f2bf(t.z); o.w = f2bf(t.w);
    *(u16x4*)(dst + (size_t)idx * 4) = o;
}

// ---------------- fused QKV GEMM + bias + RoPE + repack (BK=64) ----------------
// C = Xb[2048][2048] * Wqkv[3072][2048]^T. 128x128 tiles, BK=64, 256 thr = 4 waves;
// wave w owns rows w*32..w*32+31 x all 128 cols (acc[2][8]); RoPE partners in-lane.
// LDS granule-XOR swizzle: granule (row, c) stored at slot c^(row&7) (8 granules/row).
// tn: 0..15 Q head tn, 16..19 K head tn-16, 20..23 V kv-head tn-20 (transposed to Vt).
__global__ __launch_bounds__(256) void gemm_qkv_rope(const u16* __restrict__ A, const u16* __restrict__ B,
                                                     const float* __restrict__ bias,
                                                     u16* __restrict__ Qr, u16* __restrict__ Kr,
                                                     u16* __restrict__ Vt) {
    const int K = 2048;
    __shared__ u16 As[128 * 64];
    __shared__ u16 Bs[128 * 64];
    const int tm = blockIdx.y, tn = blockIdx.x;
    const int tid = threadIdx.x;
    const int w = tid >> 6, lane = tid & 63, quad = lane >> 4, l16 = lane & 15;

    f4 acc[2][8];
#pragma unroll
    for (int i = 0; i < 2; i++)
#pragma unroll
        for (int j = 0; j < 8; j++) acc[i][j] = f4{0.f, 0.f, 0.f, 0.f};

    const int r8 = lane >> 3;                 // 0..7
    const int c8 = (lane & 7) ^ r8;           // swizzled source granule col
    const u16* aPtr = A + (size_t)(tm * 128 + w * 32 + r8) * K + c8 * 8;
    const u16* bPtr = B + (size_t)(tn * 128 + w * 32 + r8) * K + c8 * 8;
    const size_t rskip = (size_t)8 * K;       // 8 rows

    for (int k0 = 0; k0 < K; k0 += 64) {
        __syncthreads();
#pragma unroll
        for (int i = 0; i < 4; i++) {
            gload16(aPtr + i * rskip, &As[(w * 4 + i) * 512]);
            gload16(bPtr + i * rskip, &Bs[(w * 4 + i) * 512]);
        }
        aPtr += 64; bPtr += 64;
        __syncthreads();

#pragma unroll
        for (int s = 0; s < 2; s++) {
            bfrag af[2], bf[8];
#pragma unroll
            for (int i = 0; i < 2; i++)
                af[i] = *(const bfrag*)(&As[(w * 32 + i * 16 + l16) * 64 + (((s * 4 + quad) ^ (l16 & 7)) * 8)]);
#pragma unroll
            for (int j = 0; j < 8; j++)
                bf[j] = *(const bfrag*)(&Bs[(j * 16 + l16) * 64 + (((s * 4 + quad) ^ (l16 & 7)) * 8)]);
#pragma unroll
            for (int i = 0; i < 2; i++)
#pragma unroll
                for (int j = 0; j < 8; j++)
                    acc[i][j] = __builtin_amdgcn_mfma_f32_16x16x32_bf16(af[i], bf[j], acc[i][j], 0, 0, 0);
        }
    }

    // ---- epilogue ----
    if (tn < 20) {   // Q or K: bias + RoPE + head-major write
        const int qk = (tn < 16);
        const int hd = qk ? tn : (tn - 16);
        u16* base = qk ? (Qr + (size_t)hd * 2048 * 128) : (Kr + (size_t)hd * 2048 * 128);
        float bia0[4], bia1[4], inv[4];
#pragma unroll
        for (int j = 0; j < 4; j++) {
            const int ip = j * 16 + l16;
            bia0[j] = bias[tn * 128 + ip];
            bia1[j] = bias[tn * 128 + ip + 64];
            inv[j] = exp2f(-(float)ip * L2T);
        }
#pragma unroll
        for (int i = 0; i < 2; i++) {
            const int s0 = tm * 128 + w * 32 + i * 16 + quad * 4;
#pragma unroll
            for (int r = 0; r < 4; r++) {
                const int s = s0 + r;
                const float fs = (float)s;
                u16* rowp = base + (size_t)s * 128;
#pragma unroll
                for (int j = 0; j < 4; j++) {
                    const int ip = j * 16 + l16;
                    float sn, cs;
                    __sincosf(fs * inv[j], &sn, &cs);
                    const float a0 = acc[i][j][r] + bia0[j];
                    const float a1 = acc[i][j + 4][r] + bia1[j];
                    rowp[ip]      = f2bf(a0 * cs - a1 * sn);
                    rowp[ip + 64] = f2bf(a1 * cs + a0 * sn);
                }
            }
        }
    } else {         // V: bias + transposed write to Vt[4][128][2048]
        const int kvh = tn - 20;
#pragma unroll
        for (int j = 0; j < 8; j++) {
            const int d = j * 16 + l16;
            const float bv = bias[tn * 128 + d];
            u16* base = Vt + ((size_t)(kvh * 128 + d)) * 2048;
#pragma unroll
            for (int i = 0; i < 2; i++) {
                const int s0 = tm * 128 + w * 32 + i * 16 + quad * 4;
                u16x4 o;
#pragma unroll
                for (int r = 0; r < 4; r++) o[r] = f2bf(acc[i][j][r] + bv);
                *(u16x4*)(base + s0) = o;
            }
        }
    }
}

// ---------------- GEMM: C[M][N] = A[M][K](bf16) * B[N][K]^T(bf16), fp32 out (BK=64) ----------------
// 128x128 tile, 256 threads = 4 waves (2x2), granule-XOR swizzled LDS, global_load_lds staging.
__global__ __launch_bounds__(256) void gemm_bt(const u16* __restrict__ A, const u16* __restrict__ B,
                                               float* __restrict__ C, int M, int N, int K) {
    __shared__ u16 As[128 * 64];
    __shared__ u16 Bs[128 * 64];
    const int tm = blockIdx.y, tn = blockIdx.x;
    const int tid = threadIdx.x;
    const int w = tid >> 6, lane = tid & 63, quad = lane >> 4, l16 = lane & 15;
    const int wm = w >> 1, wn = w & 1;

    f4 acc[4][4];
#pragma unroll
    for (int i = 0; i < 4; i++)
#pragma unroll
        for (int j = 0; j < 4; j++) acc[i][j] = f4{0.f, 0.f, 0.f, 0.f};

    const int r8 = lane >> 3;
    const int c8 = (lane & 7) ^ r8;
    const u16* aPtr = A + (size_t)(tm * 128 + w * 32 + r8) * K + c8 * 8;
    const u16* bPtr = B + (size_t)(tn * 128 + w * 32 + r8) * K + c8 * 8;
    const size_t rskip = (size_t)8 * K;

    for (int k0 = 0; k0 < K; k0 += 64) {
        __syncthreads();
#pragma unroll
        for (int i = 0; i < 4; i++) {
            gload16(aPtr + i * rskip, &As[(w * 4 + i) * 512]);
            gload16(bPtr + i * rskip, &Bs[(w * 4 + i) * 512]);
        }
        aPtr += 64; bPtr += 64;
        __syncthreads();

#pragma unroll
        for (int s = 0; s < 2; s++) {
            bfrag af[4], bf[4];
#pragma unroll
            for (int i = 0; i < 4; i++)
                af[i] = *(const bfrag*)(&As[(wm * 64 + i * 16 + l16) * 64 + (((s * 4 + quad) ^ (l16 & 7)) * 8)]);
#pragma unroll
            for (int j = 0; j < 4; j++)
                bf[j] = *(const bfrag*)(&Bs[(wn * 64 + j * 16 + l16) * 64 + (((s * 4 + quad) ^ (l16 & 7)) * 8)]);
#pragma unroll
            for (int i = 0; i < 4; i++)
#pragma unroll
                for (int j = 0; j < 4; j++)
                    acc[i][j] = __builtin_amdgcn_mfma_f32_16x16x32_bf16(af[i], bf[j], acc[i][j], 0, 0, 0);
        }
    }

#pragma unroll
    for (int i = 0; i < 4; i++) {
#pragma unroll
        for (int j = 0; j < 4; j++) {
            const int col = tn * 128 + wn * 64 + j * 16 + l16;
#pragma unroll
            for (int r = 0; r < 4; r++) {
                const int row = tm * 128 + wm * 64 + i * 16 + quad * 4 + r;
                C[(size_t)row * N + col] = acc[i][j][r];
            }
        }
    }
}

// ---------------- flash attention (causal), S^T formulation, 128-key tiles ----------------
// 512 blocks x 256 threads = 4 waves. Block = (kv head, 16-row q-group g); wave w = q-head
// kv*4+w on the same 16 rows (GQA-shared staging). S^T via swapped-operand 16x16x32 MFMA:
// lane holds P[q=l16][key=nt*16+quad*4+r]. PV uses full-rate 16x16x32 with a PERMUTED
// k-slot<->key map (k=quad*8+j <-> key=(j>>2)*16+quad*4+(j&3)): the B-frag is then the
// lane's own packed pk[2c],pk[2c+1] (no shuffles, no LDS round-trip); A-frag = two b64
// V^T reads. O accumulated as O[d=ct*16+quad*4+r][q=l16]. Streaming softmax.
__global__ __launch_bounds__(256) void flash_attn(const u16* __restrict__ Qr, const u16* __restrict__ Kr,
                                                  const u16* __restrict__ Vt, u16* __restrict__ attnout) {
    const int bid = blockIdx.x;
    const int kv = bid & 3;
    const int gy = bid >> 2;          // 0..127
    const int g = ((gy & 1) << 6) | ((gy & 2) << 4) | ((gy & 4) << 2) | (gy & 8) |
                  ((gy & 16) >> 2) | ((gy & 32) >> 4) | ((gy & 64) >> 6);   // bitrev7
    const int tid = threadIdx.x;
    const int w = tid >> 6, lane = tid & 63, quad = lane >> 4, l16 = lane & 15;
    const int h = kv * 4 + w;         // wave's q-head

    __shared__ u16 ks[128 * 128];     // K tile [128 keys][128 d], swizzled 16B granules
    __shared__ u16 vt[128 * 128];     // V^T tile [128 d][128 keys], swizzled 16B granules

    // Q fragments (B-operand layout: rows q=l16, k at quad*8)
    bfrag aq[4];
    const u16* qbase = Qr + ((size_t)(h * 2048 + g * 16 + l16)) * 128 + quad * 8;
#pragma unroll
    for (int kb = 0; kb < 4; kb++) aq[kb] = *(const bfrag*)(qbase + kb * 32);

    f4 oacc[8];
#pragma unroll
    for (int ct = 0; ct < 8; ct++) oacc[ct] = f4{0.f, 0.f, 0.f, 0.f};
    float psum = 0.f;                 // per-lane partial row-sum for q = l16

    const int qg = g * 16 + l16;      // this lane's global q row
    const int ktn = g / 8 + 1;        // 128-key tiles for rows [g*16, g*16+16)
    const float C = 0.08838834764831845f * 1.4426950408889634f;  // (1/sqrt(128))*log2(e)
    const u16* kbase = Kr + (size_t)kv * 2048 * 128;
    const u16* vbase = Vt + (size_t)kv * 128 * 2048;

    for (int kt = 0; kt < ktn; kt++) {
        __syncthreads();
        // stage K [128 keys][128 d]: 2048 granules, 8/thread, slot c^(row&15)
#pragma unroll
        for (int i = 0; i < 8; i++) {
            const int ci = (w * 8 + i) * 64 + lane;
            const int r = ci >> 4, c = (ci & 15) ^ (r & 15);
            gload16(kbase + (size_t)(kt * 128 + r) * 128 + c * 8, &ks[(w * 8 + i) * 512]);
        }
        // stage V^T [128 d][128 keys]: 2048 granules
#pragma unroll
        for (int i = 0; i < 8; i++) {
            const int ci = (w * 8 + i) * 64 + lane;
            const int r = ci >> 4, c = (ci & 15) ^ (r & 15);
            gload16(vbase + (size_t)r * 2048 + kt * 128 + c * 8, &vt[(w * 8 + i) * 512]);
        }
        __syncthreads();

        // S^T: D[key][q] over 128 keys; A = K-frag (rows key), B = aq
        f4 sc[8];
#pragma unroll
        for (int nt = 0; nt < 8; nt++) {
            f4 c = f4{0.f, 0.f, 0.f, 0.f};
#pragma unroll
            for (int kb = 0; kb < 4; kb++) {
                bfrag a = *(const bfrag*)(&ks[((nt * 16 + l16) * 16 + ((quad + kb * 4) ^ l16)) * 8]);
                c = __builtin_amdgcn_mfma_f32_16x16x32_bf16(a, aq[kb], c, 0, 0, 0);
            }
            sc[nt] = c;
        }

        if (kt == ktn - 1) {          // only the last tile needs causal masking
#pragma unroll
            for (int nt = 0; nt < 8; nt++) {
                const int key = kt * 128 + nt * 16 + quad * 4;
#pragma unroll
                for (int r = 0; r < 4; r++)
                    if (key + r > qg) sc[nt][r] = -INFINITY;
            }
        }

        // streaming softmax + in-lane P pack: pk[nt] = bf16(exp2(clamp(s*C)))
        s4 pk[8];
#pragma unroll
        for (int nt = 0; nt < 8; nt++) {
#pragma unroll
            for (int r = 0; r < 4; r++) {
                const float p = exp2f(fminf(sc[nt][r] * C, 40.f));
                psum += p;
                pk[nt][r] = (short)f2bf(p);
            }
        }

        // O += P*V, full-rate 16x16x32 with permuted k-map; B = {pk[2c], pk[2c+1]} in-lane
#pragma unroll
        for (int c = 0; c < 4; c++) {
            bfrag bv;
#pragma unroll
            for (int e = 0; e < 4; e++) { bv[e] = pk[2 * c][e]; bv[e + 4] = pk[2 * c + 1][e]; }
            const int sl0 = ((c * 4 + (quad >> 1)) ^ l16) * 8 + (quad & 1) * 4;
            const int sl1 = ((c * 4 + 2 + (quad >> 1)) ^ l16) * 8 + (quad & 1) * 4;
#pragma unroll
            for (int ct = 0; ct < 8; ct++) {
                const int d = ct * 16 + l16;
                s4 a0 = *(const s4*)(&vt[d * 128 + sl0]);
                s4 a1 = *(const s4*)(&vt[d * 128 + sl1]);
                bfrag av;
#pragma unroll
                for (int e = 0; e < 4; e++) { av[e] = a0[e]; av[e + 4] = a1[e]; }
                oacc[ct] = __builtin_amdgcn_mfma_f32_16x16x32_bf16(av, bv, oacc[ct], 0, 0, 0);
            }
        }
    }

    // epilogue: reduce psum over the 4 quads sharing q=l16, normalize, vector-store
    float s = psum;
    s += __shfl_xor(s, 16, 64);
    s += __shfl_xor(s, 32, 64);
    const float inv_l = 1.0f / s;
    u16* orow = attnout + (size_t)qg * 2048 + h * 128;
#pragma unroll
    for (int ct = 0; ct < 8; ct++) {
        u16x4 o;
#pragma unroll
        for (int r = 0; r < 4; r++) o[r] = f2bf(oacc[ct][r] * inv_l);
        *(u16x4*)(orow + ct * 16 + quad * 4) = o;
    }
}

// ---------------- launch ----------------
extern "C" void kernel_launch(void* const* d_in, const int* in_sizes, int n_in,
                              void* d_out, int out_size, void* d_ws, size_t ws_size,
                              hipStream_t stream) {
    const float* X  = (const float*)d_in[0];
    const float* wq = (const float*)d_in[3];
    const float* bq = (const float*)d_in[4];
    const float* wk = (const float*)d_in[5];
    const float* bk = (const float*)d_in[6];
    const float* wv = (const float*)d_in[7];
    const float* bv = (const float*)d_in[8];
    const float* wo = (const float*)d_in[9];

    char* ws = (char*)d_ws;
    u16*   Xb      = (u16*)(ws);                         // 8 MB
    u16*   Wqkv    = (u16*)(ws + 8388608);               // 12 MB  [3072][2048]
    u16*   Wo      = (u16*)(ws + 20971520);              // 8 MB
    float* biasqkv = (float*)(ws + 29360128);            // 12 KB
    u16*   Qr      = (u16*)(ws + 54538240);              // 8 MB   [16][2048][128]
    u16*   Kr      = (u16*)(ws + 62926848);              // 2 MB   [4][2048][128]
    u16*   attnout = (u16*)(ws + 67121152);              // 8 MB   [2048][2048]
    u16*   Vt      = (u16*)(ws + 75509760);              // 2 MB   [4][128][2048]

    prep<<<14339, 256, 0, stream>>>(X, wq, wk, wv, wo, bq, bk, bv, Xb, Wqkv, Wo, biasqkv);
    gemm_qkv_rope<<<dim3(24, 16), 256, 0, stream>>>(Xb, Wqkv, biasqkv, Qr, Kr, Vt);
    flash_attn<<<512, 256, 0, stream>>>(Qr, Kr, Vt, attnout);
    gemm_bt<<<dim3(16, 16), 256, 0, stream>>>(attnout, Wo, (float*)d_out, 2048, 2048, 2048);
}